// Round 1
// baseline (430.214 us; speedup 1.0000x reference)
//
#include <hip/hip_runtime.h>
#include <math.h>
#include <cstdint>
#include <cstddef>

#define DI __device__ __forceinline__

typedef __bf16 bf16x8 __attribute__((ext_vector_type(8)));
typedef float f32x4 __attribute__((ext_vector_type(4)));

static constexpr int kB = 4, kS = 2048, kD = 1024;
static constexpr int kM = kB * kS;            // 8192 tokens
static constexpr float kScale = 0.03125f;     // 1/sqrt(1024)
static constexpr float kEps = 1e-5f;

DI unsigned short f2bf(float f) {
  unsigned u = __float_as_uint(f);
  u += 0x7FFFu + ((u >> 16) & 1u);   // round-to-nearest-even
  return (unsigned short)(u >> 16);
}

DI void gld_lds16(const void* g, void* l) {
  __builtin_amdgcn_global_load_lds(
      (__attribute__((address_space(1))) void*)(void*)g,
      (__attribute__((address_space(3))) void*)l, 16, 0, 0);
}

// ---------------- cast fp32 -> bf16, 4 elems/thread ----------------
__global__ __launch_bounds__(256) void k_cast_bf16(const float* __restrict__ in,
                                                   unsigned short* __restrict__ out,
                                                   int n4) {
  int i = blockIdx.x * 256 + threadIdx.x;
  if (i >= n4) return;
  float4 v = ((const float4*)in)[i];
  ushort4 o;
  o.x = f2bf(v.x); o.y = f2bf(v.y); o.z = f2bf(v.z); o.w = f2bf(v.w);
  ((ushort4*)out)[i] = o;
}

// ---------------- generic bf16 NT GEMM ----------------
// C[M,N] = A[M,K] * B[N,K]^T  (+bias, optional relu), batched via blockIdx.z.
// CAUSAL: 0 none; 1 skip blocks fully above diagonal (scores GEMM);
//         2 clamp K-loop at bm+128 (attn GEMM: P[q][k]=0 for k>q).
// 128x128 tile, BK=64, 4 waves x (4x4) frags of mfma_f32_16x16x32_bf16.
template <int OUT_BF16, int RELU, int CAUSAL>
__global__ __launch_bounds__(256, 2) void k_gemm_nt(
    const unsigned short* __restrict__ A, const unsigned short* __restrict__ B,
    void* __restrict__ Cv, const float* __restrict__ bias,
    int M, int N, int K, long sA, long sB, long sC) {
  const int bm = blockIdx.y * 128;
  const int bn = blockIdx.x * 128;
  if (CAUSAL == 1 && bn > bm + 127) return;  // fully masked tile
  A += (long)blockIdx.z * sA;
  B += (long)blockIdx.z * sB;
  const int Keff = (CAUSAL == 2) ? ((K < bm + 128) ? K : bm + 128) : K;

  const int tid = threadIdx.x;
  const int lane = tid & 63;
  const int wm = ((tid >> 6) >> 1) * 64;   // wave row offset in tile
  const int wn = ((tid >> 6) & 1) * 64;    // wave col offset in tile

  __shared__ __align__(16) unsigned short Asm[128 * 64];
  __shared__ __align__(16) unsigned short Bsm[128 * 64];

  f32x4 acc[4][4];
#pragma unroll
  for (int i = 0; i < 4; ++i)
#pragma unroll
    for (int j = 0; j < 4; ++j) acc[i][j] = (f32x4){0.f, 0.f, 0.f, 0.f};

  const int r_row = tid >> 3;      // 0..31 : tile row within 32-row stripe
  const int r_k = (tid & 7) * 8;   // 0,8,..,56 : k offset (8 bf16 = 16B)
  const int fm = lane & 15;
  const int fq = lane >> 4;        // quad 0..3

  for (int k0 = 0; k0 < Keff; k0 += 64) {
#pragma unroll
    for (int i = 0; i < 4; ++i) {
      const int row = i * 32 + r_row;
      // LDS layout [row][k] stride 64 -> byte off = tid*16 + i*4096 (lane-contiguous)
      gld_lds16(A + (long)(bm + row) * K + (k0 + r_k), Asm + row * 64 + r_k);
      gld_lds16(B + (long)(bn + row) * K + (k0 + r_k), Bsm + row * 64 + r_k);
    }
    __syncthreads();
#pragma unroll
    for (int kk = 0; kk < 2; ++kk) {
      bf16x8 af[4], bfr[4];
#pragma unroll
      for (int i = 0; i < 4; ++i) {
        af[i]  = *(const bf16x8*)(Asm + (wm + i * 16 + fm) * 64 + kk * 32 + fq * 8);
        bfr[i] = *(const bf16x8*)(Bsm + (wn + i * 16 + fm) * 64 + kk * 32 + fq * 8);
      }
#pragma unroll
      for (int i = 0; i < 4; ++i)
#pragma unroll
        for (int j = 0; j < 4; ++j)
          acc[i][j] = __builtin_amdgcn_mfma_f32_16x16x32_bf16(af[i], bfr[j], acc[i][j], 0, 0, 0);
    }
    __syncthreads();
  }

  const long cb = (long)blockIdx.z * sC;
#pragma unroll
  for (int i = 0; i < 4; ++i) {
#pragma unroll
    for (int j = 0; j < 4; ++j) {
      const int col = bn + wn + j * 16 + fm;       // C/D: col = lane&15
      const float bv = bias ? bias[col] : 0.f;
#pragma unroll
      for (int r = 0; r < 4; ++r) {
        const int row = bm + wm + i * 16 + fq * 4 + r;  // row = quad*4 + reg
        float v = acc[i][j][r] + bv;
        if (RELU) v = fmaxf(v, 0.f);
        if (OUT_BF16)
          ((unsigned short*)Cv)[cb + (long)row * N + col] = f2bf(v);
        else
          ((float*)Cv)[cb + (long)row * N + col] = v;
      }
    }
  }
}

// ---------------- wave reductions ----------------
DI float wsum(float v) {
  v += __shfl_xor(v, 32, 64);
  v += __shfl_xor(v, 16, 64);
  v += __shfl_xor(v, 8, 64);
  v += __shfl_xor(v, 4, 64);
  v += __shfl_xor(v, 2, 64);
  v += __shfl_xor(v, 1, 64);
  return v;
}
DI float wmax(float v) {
  v = fmaxf(v, __shfl_xor(v, 32, 64));
  v = fmaxf(v, __shfl_xor(v, 16, 64));
  v = fmaxf(v, __shfl_xor(v, 8, 64));
  v = fmaxf(v, __shfl_xor(v, 4, 64));
  v = fmaxf(v, __shfl_xor(v, 2, 64));
  v = fmaxf(v, __shfl_xor(v, 1, 64));
  return v;
}

// ---------------- causal softmax: scores fp32 -> P bf16 ----------------
// one block per (b,q) row; row resident in registers (8 els/thread).
__global__ __launch_bounds__(256) void k_softmax_causal(const float* __restrict__ S,
                                                        unsigned short* __restrict__ P) {
  const int row = blockIdx.x;           // 0..8191 flat (b*2048+q)
  const int q = row & (kS - 1);
  const float* Srow = S + (long)row * kS;
  unsigned short* Prow = P + (long)row * kS;
  const int tid = threadIdx.x;
  __shared__ float red[4];

  float v[8];
  float mx = -INFINITY;
#pragma unroll
  for (int i = 0; i < 8; ++i) {
    const int k = tid + i * 256;
    float xv = -INFINITY;
    if (k <= q) xv = Srow[k] * kScale;
    v[i] = xv;
    mx = fmaxf(mx, xv);
  }
  mx = wmax(mx);
  if ((tid & 63) == 0) red[tid >> 6] = mx;
  __syncthreads();
  mx = fmaxf(fmaxf(red[0], red[1]), fmaxf(red[2], red[3]));
  __syncthreads();  // red reused below

  float sum = 0.f;
#pragma unroll
  for (int i = 0; i < 8; ++i) {
    const float e = (v[i] > -INFINITY) ? __expf(v[i] - mx) : 0.f;
    v[i] = e;
    sum += e;
  }
  sum = wsum(sum);
  if ((tid & 63) == 0) red[tid >> 6] = sum;
  __syncthreads();
  sum = red[0] + red[1] + red[2] + red[3];
  const float inv = 1.f / sum;
#pragma unroll
  for (int i = 0; i < 8; ++i) Prow[tid + i * 256] = f2bf(v[i] * inv);
}

// ---------------- fused residual + layernorm ----------------
// out = LN(X + Y) * gamma + beta; optionally also bf16 copy.
template <int WRITE_BF16>
__global__ __launch_bounds__(256) void k_residual_ln(
    const float* __restrict__ X, const float* __restrict__ Y,
    const float* __restrict__ gamma, const float* __restrict__ beta,
    float* __restrict__ Out, unsigned short* __restrict__ OutB) {
  const long base = (long)blockIdx.x * kD;
  const int tid = threadIdx.x;
  __shared__ float reds[4], redss[4];
  float v[4];
  float s = 0.f, ss2 = 0.f;
#pragma unroll
  for (int i = 0; i < 4; ++i) {
    const int k = tid + i * 256;
    const float xv = X[base + k] + Y[base + k];
    v[i] = xv;
    s += xv;
    ss2 += xv * xv;
  }
  s = wsum(s);
  ss2 = wsum(ss2);
  if ((tid & 63) == 0) { reds[tid >> 6] = s; redss[tid >> 6] = ss2; }
  __syncthreads();
  s = reds[0] + reds[1] + reds[2] + reds[3];
  ss2 = redss[0] + redss[1] + redss[2] + redss[3];
  const float mu = s * (1.f / kD);
  float var = ss2 * (1.f / kD) - mu * mu;
  var = fmaxf(var, 0.f);
  const float rstd = rsqrtf(var + kEps);
#pragma unroll
  for (int i = 0; i < 4; ++i) {
    const int k = tid + i * 256;
    const float y = (v[i] - mu) * rstd * gamma[k] + beta[k];
    Out[base + k] = y;
    if (WRITE_BF16) OutB[base + k] = f2bf(y);
  }
}

// ---------------- bf16 transpose (per batch, 64x64 tiles) ----------------
__global__ __launch_bounds__(256) void k_transpose_bf16(
    const unsigned short* __restrict__ in, unsigned short* __restrict__ out,
    int rows, int cols) {
  __shared__ unsigned short tile[64][65];
  const long ib = (long)blockIdx.z * rows * cols;
  const int c0 = blockIdx.x * 64, r0 = blockIdx.y * 64;
  const int tx = threadIdx.x & 63;
  const int ty = threadIdx.x >> 6;
#pragma unroll
  for (int i = 0; i < 16; ++i) {
    const int r = ty + i * 4;
    tile[r][tx] = in[ib + (long)(r0 + r) * cols + (c0 + tx)];
  }
  __syncthreads();
#pragma unroll
  for (int i = 0; i < 16; ++i) {
    const int c = ty + i * 4;
    out[ib + (long)(c0 + c) * rows + (r0 + tx)] = tile[tx][c];
  }
}

extern "C" void kernel_launch(void* const* d_in, const int* in_sizes, int n_in,
                              void* d_out, int out_size, void* d_ws, size_t ws_size,
                              hipStream_t stream) {
  (void)in_sizes; (void)n_in; (void)out_size; (void)ws_size;
  const float* x     = (const float*)d_in[0];
  const float* Wq    = (const float*)d_in[1];
  const float* Wk    = (const float*)d_in[2];
  const float* Wv    = (const float*)d_in[3];
  const float* W1    = (const float*)d_in[4];
  const float* b1    = (const float*)d_in[5];
  const float* W2    = (const float*)d_in[6];
  const float* b2    = (const float*)d_in[7];
  const float* gamma = (const float*)d_in[8];
  const float* beta  = (const float*)d_in[9];
  float* out = (float*)d_out;

  char* base = (char*)d_ws;
  size_t off = 0;
  auto alloc = [&](size_t bytes) -> void* {
    void* p = base + off;
    off = (off + bytes + 255) & ~(size_t)255;
    return p;
  };

  unsigned short* xb  = (unsigned short*)alloc((size_t)kM * kD * 2);
  unsigned short* Wqb = (unsigned short*)alloc((size_t)kD * kD * 2);
  unsigned short* Wkb = (unsigned short*)alloc((size_t)kD * kD * 2);
  unsigned short* Wvb = (unsigned short*)alloc((size_t)kD * kD * 2);
  unsigned short* W1b = (unsigned short*)alloc((size_t)kD * kD * 2);
  unsigned short* W2b = (unsigned short*)alloc((size_t)kD * kD * 2);
  unsigned short* Qb  = (unsigned short*)alloc((size_t)kM * kD * 2);
  unsigned short* Kb  = (unsigned short*)alloc((size_t)kM * kD * 2);
  unsigned short* Vb  = (unsigned short*)alloc((size_t)kM * kD * 2);
  unsigned short* Vt  = (unsigned short*)alloc((size_t)kM * kD * 2);
  float*          scores = (float*)alloc((size_t)kB * kS * kS * 4);   // 64 MB
  unsigned short* Pb     = (unsigned short*)alloc((size_t)kB * kS * kS * 2);
  float*          h      = (float*)alloc((size_t)kM * kD * 4);
  // aliases over dead regions:
  unsigned short* hb  = Qb;                                     // Q dead after scores
  unsigned short* mid = Kb;                                     // K dead after scores
  float* attn = scores;                                         // scores dead after softmax
  float* ff   = (float*)((char*)scores + (size_t)kM * kD * 4);  // second half of scores

  dim3 blk(256);

  // casts
  k_cast_bf16<<<kM * kD / 4 / 256, blk, 0, stream>>>(x, xb, kM * kD / 4);
  k_cast_bf16<<<kD * kD / 4 / 256, blk, 0, stream>>>(Wq, Wqb, kD * kD / 4);
  k_cast_bf16<<<kD * kD / 4 / 256, blk, 0, stream>>>(Wk, Wkb, kD * kD / 4);
  k_cast_bf16<<<kD * kD / 4 / 256, blk, 0, stream>>>(Wv, Wvb, kD * kD / 4);
  k_cast_bf16<<<kD * kD / 4 / 256, blk, 0, stream>>>(W1, W1b, kD * kD / 4);
  k_cast_bf16<<<kD * kD / 4 / 256, blk, 0, stream>>>(W2, W2b, kD * kD / 4);

  // QKV projections
  k_gemm_nt<1, 0, 0><<<dim3(kD / 128, kM / 128, 1), blk, 0, stream>>>(
      xb, Wqb, Qb, nullptr, kM, kD, kD, 0, 0, 0);
  k_gemm_nt<1, 0, 0><<<dim3(kD / 128, kM / 128, 1), blk, 0, stream>>>(
      xb, Wkb, Kb, nullptr, kM, kD, kD, 0, 0, 0);
  k_gemm_nt<1, 0, 0><<<dim3(kD / 128, kM / 128, 1), blk, 0, stream>>>(
      xb, Wvb, Vb, nullptr, kM, kD, kD, 0, 0, 0);

  // V -> V^T per batch
  k_transpose_bf16<<<dim3(kD / 64, kS / 64, kB), blk, 0, stream>>>(Vb, Vt, kS, kD);

  // scores = Q K^T (causal tile skip; scale folded into softmax)
  k_gemm_nt<0, 0, 1><<<dim3(kS / 128, kS / 128, kB), blk, 0, stream>>>(
      Qb, Kb, scores, nullptr, kS, kS, kD,
      (long)kS * kD, (long)kS * kD, (long)kS * kS);

  // causal softmax -> P bf16
  k_softmax_causal<<<kM, blk, 0, stream>>>(scores, Pb);

  // attn = P Vt^T (K-loop clamped at the diagonal)
  k_gemm_nt<0, 0, 2><<<dim3(kD / 128, kS / 128, kB), blk, 0, stream>>>(
      Pb, Vt, attn, nullptr, kS, kD, kS,
      (long)kS * kS, (long)kD * kS, (long)kS * kD);

  // h = LN(x + attn), also bf16 copy
  k_residual_ln<1><<<kM, blk, 0, stream>>>(x, attn, gamma, beta, h, hb);

  // FFN
  k_gemm_nt<1, 1, 0><<<dim3(kD / 128, kM / 128, 1), blk, 0, stream>>>(
      hb, W1b, mid, b1, kM, kD, kD, 0, 0, 0);
  k_gemm_nt<0, 0, 0><<<dim3(kD / 128, kM / 128, 1), blk, 0, stream>>>(
      mid, W2b, ff, b2, kM, kD, kD, 0, 0, 0);

  // out = LN(h + ff)
  k_residual_ln<0><<<kM, blk, 0, stream>>>(h, ff, gamma, beta, out, nullptr);
}

// Round 3
// 365.350 us; speedup vs baseline: 1.1775x; 1.1775x over previous
//
#include <hip/hip_runtime.h>
#include <math.h>
#include <cstdint>
#include <cstddef>

#define DI __device__ __forceinline__

typedef __bf16 bf16x8 __attribute__((ext_vector_type(8)));
typedef float f32x4 __attribute__((ext_vector_type(4)));

static constexpr int kB = 4, kS = 2048, kD = 1024;
static constexpr int kM = kB * kS;            // 8192 tokens
static constexpr float kScale = 0.03125f;     // 1/sqrt(1024)
static constexpr float kEps = 1e-5f;

DI unsigned short f2bf(float f) {
  unsigned u = __float_as_uint(f);
  u += 0x7FFFu + ((u >> 16) & 1u);   // round-to-nearest-even
  return (unsigned short)(u >> 16);
}

DI void gld_lds16(const void* g, void* l) {
  __builtin_amdgcn_global_load_lds(
      (__attribute__((address_space(1))) void*)(void*)g,
      (__attribute__((address_space(3))) void*)l, 16, 0, 0);
}

// ---------------- fused cast fp32 -> bf16 (x, Wq|Wk|Wv concat, W1, W2) -----
__global__ __launch_bounds__(256) void k_cast_all(
    const float* __restrict__ x, const float* __restrict__ Wq,
    const float* __restrict__ Wk, const float* __restrict__ Wv,
    const float* __restrict__ W1, const float* __restrict__ W2,
    unsigned short* __restrict__ xb, unsigned short* __restrict__ Wqkvb,
    unsigned short* __restrict__ W1b, unsigned short* __restrict__ W2b) {
  const int i = blockIdx.x * 256 + threadIdx.x;     // float4 index
  const int X4 = kM * kD / 4;                       // 2,097,152
  const int W4 = kD * kD / 4;                       // 262,144
  const float* src;
  unsigned short* dst;
  int j;
  if (i < X4) { src = x; dst = xb; j = i; }
  else if (i < X4 + W4)     { src = Wq; dst = Wqkvb;           j = i - X4; }
  else if (i < X4 + 2 * W4) { src = Wk; dst = Wqkvb + 4 * W4;  j = i - X4 - W4; }
  else if (i < X4 + 3 * W4) { src = Wv; dst = Wqkvb + 8 * W4;  j = i - X4 - 2 * W4; }
  else if (i < X4 + 4 * W4) { src = W1; dst = W1b;             j = i - X4 - 3 * W4; }
  else                      { src = W2; dst = W2b;             j = i - X4 - 4 * W4; }
  float4 v = ((const float4*)src)[j];
  ushort4 o;
  o.x = f2bf(v.x); o.y = f2bf(v.y); o.z = f2bf(v.z); o.w = f2bf(v.w);
  ((ushort4*)dst)[j] = o;
}

// ---------------- generic bf16 NT GEMM with XOR-swizzled LDS ----------------
// C[M,N] = A[M,K] * B[N,K]^T (+bias, optional relu), batched via blockIdx.z.
// CAUSAL: 0 none; 1 lower-triangle compact grid (blockIdx.x = tri index);
//         2 clamp K-loop at bm+128, longest-first y order.
// LDS tile [row][kchunk]: chunk kc of row r stored at slot kc ^ (r&7) so the
// fragment ds_read_b128 spreads across all 32 banks (8 accesses/bank = min).
// Staging keeps dst = wave-uniform base + lane*16 (global_load_lds constraint);
// the GLOBAL chunk each lane fetches is XOR-permuted within its 128B segment.
template <int OUT_BF16, int RELU, int CAUSAL>
__global__ __launch_bounds__(256, 2) void k_gemm_nt(
    const unsigned short* __restrict__ A, const unsigned short* __restrict__ B,
    void* __restrict__ Cv, const float* __restrict__ bias,
    int M, int N, int K, int lda, int ldb, int ldc,
    long sA, long sB, long sC) {
  int bm, bn;
  if (CAUSAL == 1) {
    const int t = blockIdx.x;
    int r = (int)floorf((sqrtf(8.f * (float)t + 1.f) - 1.f) * 0.5f);
    while ((r + 1) * (r + 2) / 2 <= t) ++r;
    while (r * (r + 1) / 2 > t) --r;
    bm = r * 128;
    bn = (t - r * (r + 1) / 2) * 128;
  } else if (CAUSAL == 2) {
    bm = (gridDim.y - 1 - blockIdx.y) * 128;   // longest K-loop first
    bn = blockIdx.x * 128;
  } else {
    bm = blockIdx.y * 128;
    bn = blockIdx.x * 128;
  }
  A += (long)blockIdx.z * sA;
  B += (long)blockIdx.z * sB;
  const int Keff = (CAUSAL == 2) ? ((K < bm + 128) ? K : bm + 128) : K;

  const int tid = threadIdx.x;
  const int lane = tid & 63;
  const int wm = ((tid >> 6) >> 1) * 64;   // wave row offset in tile
  const int wn = ((tid >> 6) & 1) * 64;    // wave col offset in tile

  __shared__ __align__(16) unsigned short Asm[128 * 64];
  __shared__ __align__(16) unsigned short Bsm[128 * 64];

  f32x4 acc[4][4];
#pragma unroll
  for (int i = 0; i < 4; ++i)
#pragma unroll
    for (int j = 0; j < 4; ++j) acc[i][j] = (f32x4){0.f, 0.f, 0.f, 0.f};

  const int r_row = tid >> 3;                              // 0..31
  const int dst_k = (tid & 7) * 8;                         // LDS slot (linear)
  const int src_k = ((tid & 7) ^ ((tid >> 3) & 7)) * 8;    // swizzled global chunk
  const int fm = lane & 15;
  const int fq = lane >> 4;                                // quad 0..3

  for (int k0 = 0; k0 < Keff; k0 += 64) {
#pragma unroll
    for (int i = 0; i < 4; ++i) {
      const int row = i * 32 + r_row;
      gld_lds16(A + (long)(bm + row) * lda + (k0 + src_k), Asm + row * 64 + dst_k);
      gld_lds16(B + (long)(bn + row) * ldb + (k0 + src_k), Bsm + row * 64 + dst_k);
    }
    __syncthreads();
#pragma unroll
    for (int kk = 0; kk < 2; ++kk) {
      bf16x8 af[4], bfr[4];
#pragma unroll
      for (int i = 0; i < 4; ++i) {
        const int pa = ((kk * 4 + fq) ^ (fm & 7)) * 8;
        af[i]  = *(const bf16x8*)(Asm + (wm + i * 16 + fm) * 64 + pa);
        bfr[i] = *(const bf16x8*)(Bsm + (wn + i * 16 + fm) * 64 + pa);
      }
#pragma unroll
      for (int i = 0; i < 4; ++i)
#pragma unroll
        for (int j = 0; j < 4; ++j)
          acc[i][j] = __builtin_amdgcn_mfma_f32_16x16x32_bf16(af[i], bfr[j], acc[i][j], 0, 0, 0);
    }
    __syncthreads();
  }

  const long cb = (long)blockIdx.z * sC;
#pragma unroll
  for (int i = 0; i < 4; ++i) {
#pragma unroll
    for (int j = 0; j < 4; ++j) {
      const int col = bn + wn + j * 16 + fm;       // C/D: col = lane&15
      const float bv = bias ? bias[col] : 0.f;
#pragma unroll
      for (int r = 0; r < 4; ++r) {
        const int row = bm + wm + i * 16 + fq * 4 + r;  // row = quad*4 + reg
        float v = acc[i][j][r] + bv;
        if (RELU) v = fmaxf(v, 0.f);
        if (OUT_BF16)
          ((unsigned short*)Cv)[cb + (long)row * ldc + col] = f2bf(v);
        else
          ((float*)Cv)[cb + (long)row * ldc + col] = v;
      }
    }
  }
}

// ---------------- wave reductions ----------------
DI float wsum(float v) {
  v += __shfl_xor(v, 32, 64);
  v += __shfl_xor(v, 16, 64);
  v += __shfl_xor(v, 8, 64);
  v += __shfl_xor(v, 4, 64);
  v += __shfl_xor(v, 2, 64);
  v += __shfl_xor(v, 1, 64);
  return v;
}
DI float wmax(float v) {
  v = fmaxf(v, __shfl_xor(v, 32, 64));
  v = fmaxf(v, __shfl_xor(v, 16, 64));
  v = fmaxf(v, __shfl_xor(v, 8, 64));
  v = fmaxf(v, __shfl_xor(v, 4, 64));
  v = fmaxf(v, __shfl_xor(v, 2, 64));
  v = fmaxf(v, __shfl_xor(v, 1, 64));
  return v;
}

// ---------------- causal softmax: scores fp32 -> P bf16 ----------------
__global__ __launch_bounds__(256) void k_softmax_causal(const float* __restrict__ S,
                                                        unsigned short* __restrict__ P) {
  const int row = blockIdx.x;           // 0..8191 flat (b*2048+q)
  const int q = row & (kS - 1);
  const int lim = (q & ~127) + 128;     // attn GEMM reads only k < lim
  const float* Srow = S + (long)row * kS;
  unsigned short* Prow = P + (long)row * kS;
  const int tid = threadIdx.x;
  __shared__ float red[4];

  float v[8];
  float mx = -INFINITY;
#pragma unroll
  for (int i = 0; i < 8; ++i) {
    const int k = tid + i * 256;
    float xv = -INFINITY;
    if (k <= q) xv = Srow[k] * kScale;
    v[i] = xv;
    mx = fmaxf(mx, xv);
  }
  mx = wmax(mx);
  if ((tid & 63) == 0) red[tid >> 6] = mx;
  __syncthreads();
  mx = fmaxf(fmaxf(red[0], red[1]), fmaxf(red[2], red[3]));
  __syncthreads();  // red reused below

  float sum = 0.f;
#pragma unroll
  for (int i = 0; i < 8; ++i) {
    const float e = (v[i] > -INFINITY) ? __expf(v[i] - mx) : 0.f;
    v[i] = e;
    sum += e;
  }
  sum = wsum(sum);
  if ((tid & 63) == 0) red[tid >> 6] = sum;
  __syncthreads();
  sum = red[0] + red[1] + red[2] + red[3];
  const float inv = 1.f / sum;
#pragma unroll
  for (int i = 0; i < 8; ++i) {
    const int k = tid + i * 256;
    if (k < lim) Prow[k] = f2bf(v[i] * inv);
  }
}

// ---------------- fused residual + layernorm ----------------
template <int WRITE_BF16>
__global__ __launch_bounds__(256) void k_residual_ln(
    const float* __restrict__ X, const float* __restrict__ Y,
    const float* __restrict__ gamma, const float* __restrict__ beta,
    float* __restrict__ Out, unsigned short* __restrict__ OutB) {
  const long base = (long)blockIdx.x * kD;
  const int tid = threadIdx.x;
  __shared__ float reds[4], redss[4];
  float v[4];
  float s = 0.f, ss2 = 0.f;
#pragma unroll
  for (int i = 0; i < 4; ++i) {
    const int k = tid + i * 256;
    const float xv = X[base + k] + Y[base + k];
    v[i] = xv;
    s += xv;
    ss2 += xv * xv;
  }
  s = wsum(s);
  ss2 = wsum(ss2);
  if ((tid & 63) == 0) { reds[tid >> 6] = s; redss[tid >> 6] = ss2; }
  __syncthreads();
  s = reds[0] + reds[1] + reds[2] + reds[3];
  ss2 = redss[0] + redss[1] + redss[2] + redss[3];
  const float mu = s * (1.f / kD);
  float var = ss2 * (1.f / kD) - mu * mu;
  var = fmaxf(var, 0.f);
  const float rstd = rsqrtf(var + kEps);
#pragma unroll
  for (int i = 0; i < 4; ++i) {
    const int k = tid + i * 256;
    const float y = (v[i] - mu) * rstd * gamma[k] + beta[k];
    Out[base + k] = y;
    if (WRITE_BF16) OutB[base + k] = f2bf(y);
  }
}

// ---------------- bf16 transpose (per batch, 64x64 tiles) ----------------
__global__ __launch_bounds__(256) void k_transpose_bf16(
    const unsigned short* __restrict__ in, unsigned short* __restrict__ out,
    int rows, int cols, int ld_in, int ld_out, long sIn, long sOut) {
  __shared__ unsigned short tile[64][65];
  const long ib = (long)blockIdx.z * sIn;
  const long ob = (long)blockIdx.z * sOut;
  const int c0 = blockIdx.x * 64, r0 = blockIdx.y * 64;
  const int tx = threadIdx.x & 63;
  const int ty = threadIdx.x >> 6;
#pragma unroll
  for (int i = 0; i < 16; ++i) {
    const int r = ty + i * 4;
    tile[r][tx] = in[ib + (long)(r0 + r) * ld_in + (c0 + tx)];
  }
  __syncthreads();
#pragma unroll
  for (int i = 0; i < 16; ++i) {
    const int c = ty + i * 4;
    out[ob + (long)(c0 + c) * ld_out + (r0 + tx)] = tile[tx][c];
  }
}

extern "C" void kernel_launch(void* const* d_in, const int* in_sizes, int n_in,
                              void* d_out, int out_size, void* d_ws, size_t ws_size,
                              hipStream_t stream) {
  (void)in_sizes; (void)n_in; (void)out_size; (void)ws_size;
  const float* x     = (const float*)d_in[0];
  const float* Wq    = (const float*)d_in[1];
  const float* Wk    = (const float*)d_in[2];
  const float* Wv    = (const float*)d_in[3];
  const float* W1    = (const float*)d_in[4];
  const float* b1    = (const float*)d_in[5];
  const float* W2    = (const float*)d_in[6];
  const float* b2    = (const float*)d_in[7];
  const float* gamma = (const float*)d_in[8];
  const float* beta  = (const float*)d_in[9];
  float* out = (float*)d_out;

  char* base = (char*)d_ws;
  size_t off = 0;
  auto alloc = [&](size_t bytes) -> void* {
    void* p = base + off;
    off = (off + bytes + 255) & ~(size_t)255;
    return p;
  };

  unsigned short* xb    = (unsigned short*)alloc((size_t)kM * kD * 2);        // 16 MB
  unsigned short* Wqkvb = (unsigned short*)alloc((size_t)3 * kD * kD * 2);    // 6 MB
  unsigned short* W1b   = (unsigned short*)alloc((size_t)kD * kD * 2);        // 2 MB
  unsigned short* W2b   = (unsigned short*)alloc((size_t)kD * kD * 2);        // 2 MB
  unsigned short* QKVb  = (unsigned short*)alloc((size_t)kM * 3 * kD * 2);    // 48 MB
  unsigned short* Vt    = (unsigned short*)alloc((size_t)kM * kD * 2);        // 16 MB
  float*          scores = (float*)alloc((size_t)kB * kS * kS * 4);           // 64 MB
  unsigned short* Pb     = (unsigned short*)alloc((size_t)kB * kS * kS * 2);  // 32 MB
  float*          h      = (float*)alloc((size_t)kM * kD * 4);                // 32 MB
  // aliases over dead regions:
  float* attn = scores;                                         // scores dead after softmax
  float* ff   = (float*)((char*)scores + (size_t)kM * kD * 4);  // 2nd half of scores
  unsigned short* hb  = Pb;                                     // P dead after attn GEMM
  unsigned short* mid = Vt;                                     // Vt dead after attn GEMM

  dim3 blk(256);

  // fused casts (x -> xb, Wq|Wk|Wv -> Wqkvb, W1 -> W1b, W2 -> W2b)
  {
    const int n4 = (kM * kD + 5 * kD * kD) / 4;
    k_cast_all<<<n4 / 256, blk, 0, stream>>>(x, Wq, Wk, Wv, W1, W2,
                                             xb, Wqkvb, W1b, W2b);
  }

  // fused QKV projection: [8192x1024] x [3072x1024]^T -> QKV [8192x3072]
  k_gemm_nt<1, 0, 0><<<dim3(3 * kD / 128, kM / 128, 1), blk, 0, stream>>>(
      xb, Wqkvb, QKVb, nullptr, kM, 3 * kD, kD, kD, kD, 3 * kD, 0, 0, 0);

  // V -> V^T per batch (V = QKV cols [2048,3072))
  k_transpose_bf16<<<dim3(kD / 64, kS / 64, kB), blk, 0, stream>>>(
      QKVb + 2 * kD, Vt, kS, kD, 3 * kD, kS,
      (long)kS * 3 * kD, (long)kD * kS);

  // scores = Q K^T, lower-triangle compact grid (scale folded into softmax)
  k_gemm_nt<0, 0, 1><<<dim3(136, 1, kB), blk, 0, stream>>>(
      QKVb, QKVb + kD, scores, nullptr, kS, kS, kD, 3 * kD, 3 * kD, kS,
      (long)kS * 3 * kD, (long)kS * 3 * kD, (long)kS * kS);

  // causal softmax -> P bf16 (writes only k < diagonal tile edge)
  k_softmax_causal<<<kM, blk, 0, stream>>>(scores, Pb);

  // attn = P Vt^T (K-loop clamped at diagonal, longest-first)
  k_gemm_nt<0, 0, 2><<<dim3(kD / 128, kS / 128, kB), blk, 0, stream>>>(
      Pb, Vt, attn, nullptr, kS, kD, kS, kS, kS, kD,
      (long)kS * kS, (long)kD * kS, (long)kS * kD);

  // h = LN(x + attn), also bf16 copy
  k_residual_ln<1><<<kM, blk, 0, stream>>>(x, attn, gamma, beta, h, hb);

  // FFN
  k_gemm_nt<1, 1, 0><<<dim3(kD / 128, kM / 128, 1), blk, 0, stream>>>(
      hb, W1b, mid, b1, kM, kD, kD, kD, kD, kD, 0, 0, 0);
  k_gemm_nt<0, 0, 0><<<dim3(kD / 128, kM / 128, 1), blk, 0, stream>>>(
      mid, W2b, ff, b2, kM, kD, kD, kD, kD, kD, 0, 0, 0);

  // out = LN(h + ff)
  k_residual_ln<0><<<kM, blk, 0, stream>>>(h, ff, gamma, beta, out, nullptr);
}

// Round 4
// 362.966 us; speedup vs baseline: 1.1853x; 1.0066x over previous
//
#include <hip/hip_runtime.h>
#include <math.h>
#include <cstdint>
#include <cstddef>

#define DI __device__ __forceinline__

typedef __bf16 bf16x8 __attribute__((ext_vector_type(8)));
typedef float f32x16 __attribute__((ext_vector_type(16)));

static constexpr int kB = 4, kS = 2048, kD = 1024;
static constexpr int kM = kB * kS;            // 8192 tokens
static constexpr float kScale = 0.03125f;     // 1/sqrt(1024)
static constexpr float kEps = 1e-5f;

DI unsigned short f2bf(float f) {
  unsigned u = __float_as_uint(f);
  u += 0x7FFFu + ((u >> 16) & 1u);   // round-to-nearest-even
  return (unsigned short)(u >> 16);
}
DI float bf2f(unsigned short h) {
  return __uint_as_float(((unsigned)h) << 16);
}

DI void gld_lds16(const void* g, void* l) {
  __builtin_amdgcn_global_load_lds(
      (__attribute__((address_space(1))) void*)(void*)g,
      (__attribute__((address_space(3))) void*)l, 16, 0, 0);
}

// ------- fused cast fp32 -> bf16 (x, Wq|Wk concat, Wv, W1, W2) -------
__global__ __launch_bounds__(256) void k_cast_all(
    const float* __restrict__ x, const float* __restrict__ Wq,
    const float* __restrict__ Wk, const float* __restrict__ Wv,
    const float* __restrict__ W1, const float* __restrict__ W2,
    unsigned short* __restrict__ xb, unsigned short* __restrict__ Wqkb,
    unsigned short* __restrict__ Wvb, unsigned short* __restrict__ W1b,
    unsigned short* __restrict__ W2b) {
  const int i = blockIdx.x * 256 + threadIdx.x;     // float4 index
  const int X4 = kM * kD / 4;                       // 2,097,152
  const int W4 = kD * kD / 4;                       // 262,144
  const float* src;
  unsigned short* dst;
  int j;
  if (i < X4) { src = x; dst = xb; j = i; }
  else if (i < X4 + W4)     { src = Wq; dst = Wqkb;          j = i - X4; }
  else if (i < X4 + 2 * W4) { src = Wk; dst = Wqkb + 4 * W4; j = i - X4 - W4; }
  else if (i < X4 + 3 * W4) { src = Wv; dst = Wvb;           j = i - X4 - 2 * W4; }
  else if (i < X4 + 4 * W4) { src = W1; dst = W1b;           j = i - X4 - 3 * W4; }
  else                      { src = W2; dst = W2b;           j = i - X4 - 4 * W4; }
  float4 v = ((const float4*)src)[j];
  ushort4 o;
  o.x = f2bf(v.x); o.y = f2bf(v.y); o.z = f2bf(v.z); o.w = f2bf(v.w);
  ((ushort4*)dst)[j] = o;
}

// ---------------- bf16 NT GEMM, 32x32x16 MFMA, XOR-swizzled LDS -------------
// C[M,N] = A[M,K] * B[N,K]^T (+bias, optional relu), batched via blockIdx.z.
// CAUSAL: 0 none; 1 lower-triangle compact grid (blockIdx.x = tri index);
//         2 clamp K-loop at bm+128, longest-first y order.
// LDS tile [row][kchunk]: chunk kc of row r stored at slot kc ^ (r&7); the
// fragment ds_read_b128 then spreads 8 accesses/bank (minimum). Staging keeps
// dst = wave-uniform base + lane*16 (global_load_lds constraint); the GLOBAL
// chunk each lane fetches is XOR-permuted within its 128B segment.
// Each wave computes 64x64 = 2x2 frags of mfma_f32_32x32x16_bf16.
// A-frag: m = lane&31, k = (lane>>5)*8 + j. B symmetric (NT).
// C/D: col = lane&31, row = (reg&3) + 8*(reg>>2) + 4*(lane>>5)  [m74/m101].
template <int OUT_BF16, int RELU, int CAUSAL>
__global__ __launch_bounds__(256, 2) void k_gemm_nt(
    const unsigned short* __restrict__ A, const unsigned short* __restrict__ B,
    void* __restrict__ Cv, const float* __restrict__ bias,
    int M, int N, int K, int lda, int ldb, int ldc,
    long sA, long sB, long sC) {
  int bm, bn;
  if (CAUSAL == 1) {
    const int t = blockIdx.x;
    int r = (int)floorf((sqrtf(8.f * (float)t + 1.f) - 1.f) * 0.5f);
    while ((r + 1) * (r + 2) / 2 <= t) ++r;
    while (r * (r + 1) / 2 > t) --r;
    bm = r * 128;
    bn = (t - r * (r + 1) / 2) * 128;
  } else if (CAUSAL == 2) {
    bm = (gridDim.y - 1 - blockIdx.y) * 128;   // longest K-loop first
    bn = blockIdx.x * 128;
  } else {
    bm = blockIdx.y * 128;
    bn = blockIdx.x * 128;
  }
  A += (long)blockIdx.z * sA;
  B += (long)blockIdx.z * sB;
  const int Keff = (CAUSAL == 2) ? ((K < bm + 128) ? K : bm + 128) : K;

  const int tid = threadIdx.x;
  const int lane = tid & 63;
  const int wm = ((tid >> 6) >> 1) * 64;   // wave row offset in tile
  const int wn = ((tid >> 6) & 1) * 64;    // wave col offset in tile

  __shared__ __align__(16) unsigned short Asm[128 * 64];
  __shared__ __align__(16) unsigned short Bsm[128 * 64];

  f32x16 acc[2][2];
#pragma unroll
  for (int i = 0; i < 2; ++i)
#pragma unroll
    for (int j = 0; j < 2; ++j)
#pragma unroll
      for (int r = 0; r < 16; ++r) acc[i][j][r] = 0.f;

  const int r_row = tid >> 3;                              // 0..31
  const int dst_k = (tid & 7) * 8;                         // LDS slot (linear)
  const int src_k = ((tid & 7) ^ ((tid >> 3) & 7)) * 8;    // swizzled global chunk
  const int fr = lane & 31;                                // frag row/col
  const int fh = lane >> 5;                                // k-half 0/1

  for (int k0 = 0; k0 < Keff; k0 += 64) {
#pragma unroll
    for (int i = 0; i < 4; ++i) {
      const int row = i * 32 + r_row;
      gld_lds16(A + (long)(bm + row) * lda + (k0 + src_k), Asm + row * 64 + dst_k);
      gld_lds16(B + (long)(bn + row) * ldb + (k0 + src_k), Bsm + row * 64 + dst_k);
    }
    __syncthreads();
#pragma unroll
    for (int s = 0; s < 4; ++s) {           // 4 K-steps of 16
      bf16x8 af[2], bfr[2];
#pragma unroll
      for (int i = 0; i < 2; ++i) {
        const int ra = wm + i * 32 + fr;
        const int rb = wn + i * 32 + fr;
        const int sa = ((2 * s + fh) ^ (ra & 7)) * 8;
        const int sb = ((2 * s + fh) ^ (rb & 7)) * 8;
        af[i]  = *(const bf16x8*)(Asm + ra * 64 + sa);
        bfr[i] = *(const bf16x8*)(Bsm + rb * 64 + sb);
      }
#pragma unroll
      for (int i = 0; i < 2; ++i)
#pragma unroll
        for (int j = 0; j < 2; ++j)
          acc[i][j] = __builtin_amdgcn_mfma_f32_32x32x16_bf16(af[i], bfr[j], acc[i][j], 0, 0, 0);
    }
    __syncthreads();
  }

  const long cb = (long)blockIdx.z * sC;
#pragma unroll
  for (int i = 0; i < 2; ++i) {
#pragma unroll
    for (int j = 0; j < 2; ++j) {
      const int col = bn + wn + j * 32 + fr;
      const float bv = bias ? bias[col] : 0.f;
#pragma unroll
      for (int r = 0; r < 16; ++r) {
        const int row = bm + wm + i * 32 + (r & 3) + 8 * (r >> 2) + 4 * fh;
        float v = acc[i][j][r] + bv;
        if (RELU) v = fmaxf(v, 0.f);
        if (OUT_BF16)
          ((unsigned short*)Cv)[cb + (long)row * ldc + col] = f2bf(v);
        else
          ((float*)Cv)[cb + (long)row * ldc + col] = v;
      }
    }
  }
}

// ---------------- wave reductions ----------------
DI float wsum(float v) {
  v += __shfl_xor(v, 32, 64);
  v += __shfl_xor(v, 16, 64);
  v += __shfl_xor(v, 8, 64);
  v += __shfl_xor(v, 4, 64);
  v += __shfl_xor(v, 2, 64);
  v += __shfl_xor(v, 1, 64);
  return v;
}
DI float wmax(float v) {
  v = fmaxf(v, __shfl_xor(v, 32, 64));
  v = fmaxf(v, __shfl_xor(v, 16, 64));
  v = fmaxf(v, __shfl_xor(v, 8, 64));
  v = fmaxf(v, __shfl_xor(v, 4, 64));
  v = fmaxf(v, __shfl_xor(v, 2, 64));
  v = fmaxf(v, __shfl_xor(v, 1, 64));
  return v;
}

// ---------------- causal softmax: scores bf16 -> P bf16 ----------------
__global__ __launch_bounds__(256) void k_softmax_causal(
    const unsigned short* __restrict__ S, unsigned short* __restrict__ P) {
  const int row = blockIdx.x;           // 0..8191 flat (b*2048+q)
  const int q = row & (kS - 1);
  const int lim = (q & ~127) + 128;     // attn GEMM reads only k < lim
  const unsigned short* Srow = S + (long)row * kS;
  unsigned short* Prow = P + (long)row * kS;
  const int tid = threadIdx.x;
  __shared__ float red[4];

  float v[8];
  float mx = -INFINITY;
#pragma unroll
  for (int i = 0; i < 8; ++i) {
    const int k = tid + i * 256;
    float xv = -INFINITY;
    if (k <= q) xv = bf2f(Srow[k]) * kScale;
    v[i] = xv;
    mx = fmaxf(mx, xv);
  }
  mx = wmax(mx);
  if ((tid & 63) == 0) red[tid >> 6] = mx;
  __syncthreads();
  mx = fmaxf(fmaxf(red[0], red[1]), fmaxf(red[2], red[3]));
  __syncthreads();  // red reused below

  float sum = 0.f;
#pragma unroll
  for (int i = 0; i < 8; ++i) {
    const float e = (v[i] > -INFINITY) ? __expf(v[i] - mx) : 0.f;
    v[i] = e;
    sum += e;
  }
  sum = wsum(sum);
  if ((tid & 63) == 0) red[tid >> 6] = sum;
  __syncthreads();
  sum = red[0] + red[1] + red[2] + red[3];
  const float inv = 1.f / sum;
#pragma unroll
  for (int i = 0; i < 8; ++i) {
    const int k = tid + i * 256;
    if (k < lim) Prow[k] = f2bf(v[i] * inv);
  }
}

// ---------------- fused residual + layernorm ----------------
template <int WRITE_BF16>
__global__ __launch_bounds__(256) void k_residual_ln(
    const float* __restrict__ X, const float* __restrict__ Y,
    const float* __restrict__ gamma, const float* __restrict__ beta,
    float* __restrict__ Out, unsigned short* __restrict__ OutB) {
  const long base = (long)blockIdx.x * kD;
  const int tid = threadIdx.x;
  __shared__ float reds[4], redss[4];
  float v[4];
  float s = 0.f, ss2 = 0.f;
#pragma unroll
  for (int i = 0; i < 4; ++i) {
    const int k = tid + i * 256;
    const float xv = X[base + k] + Y[base + k];
    v[i] = xv;
    s += xv;
    ss2 += xv * xv;
  }
  s = wsum(s);
  ss2 = wsum(ss2);
  if ((tid & 63) == 0) { reds[tid >> 6] = s; redss[tid >> 6] = ss2; }
  __syncthreads();
  s = reds[0] + reds[1] + reds[2] + reds[3];
  ss2 = redss[0] + redss[1] + redss[2] + redss[3];
  const float mu = s * (1.f / kD);
  float var = ss2 * (1.f / kD) - mu * mu;
  var = fmaxf(var, 0.f);
  const float rstd = rsqrtf(var + kEps);
#pragma unroll
  for (int i = 0; i < 4; ++i) {
    const int k = tid + i * 256;
    const float y = (v[i] - mu) * rstd * gamma[k] + beta[k];
    Out[base + k] = y;
    if (WRITE_BF16) OutB[base + k] = f2bf(y);
  }
}

extern "C" void kernel_launch(void* const* d_in, const int* in_sizes, int n_in,
                              void* d_out, int out_size, void* d_ws, size_t ws_size,
                              hipStream_t stream) {
  (void)in_sizes; (void)n_in; (void)out_size; (void)ws_size;
  const float* x     = (const float*)d_in[0];
  const float* Wq    = (const float*)d_in[1];
  const float* Wk    = (const float*)d_in[2];
  const float* Wv    = (const float*)d_in[3];
  const float* W1    = (const float*)d_in[4];
  const float* b1    = (const float*)d_in[5];
  const float* W2    = (const float*)d_in[6];
  const float* b2    = (const float*)d_in[7];
  const float* gamma = (const float*)d_in[8];
  const float* beta  = (const float*)d_in[9];
  float* out = (float*)d_out;

  char* base = (char*)d_ws;
  size_t off = 0;
  auto alloc = [&](size_t bytes) -> void* {
    void* p = base + off;
    off = (off + bytes + 255) & ~(size_t)255;
    return p;
  };

  unsigned short* xb   = (unsigned short*)alloc((size_t)kM * kD * 2);        // 16 MB
  unsigned short* Wqkb = (unsigned short*)alloc((size_t)2 * kD * kD * 2);    // 4 MB
  unsigned short* Wvb  = (unsigned short*)alloc((size_t)kD * kD * 2);        // 2 MB
  unsigned short* W1b  = (unsigned short*)alloc((size_t)kD * kD * 2);        // 2 MB
  unsigned short* W2b  = (unsigned short*)alloc((size_t)kD * kD * 2);        // 2 MB
  unsigned short* QKb  = (unsigned short*)alloc((size_t)kM * 2 * kD * 2);    // 32 MB
  unsigned short* Vt   = (unsigned short*)alloc((size_t)kM * kD * 2);        // 16 MB
  unsigned short* Sb   = (unsigned short*)alloc((size_t)kB * kS * kS * 2);   // 32 MB
  unsigned short* Pb   = (unsigned short*)alloc((size_t)kB * kS * kS * 2);   // 32 MB
  float*          attn = (float*)alloc((size_t)kM * kD * 4);                 // 32 MB
  float*          h    = (float*)alloc((size_t)kM * kD * 4);                 // 32 MB
  float*          ff   = attn;               // attn dead after LN1
  unsigned short* hb   = Sb;                 // scores dead after softmax
  unsigned short* mid  = Pb;                 // P dead after attn GEMM

  dim3 blk(256);

  // fused casts
  {
    const int n4 = (kM * kD + 5 * kD * kD) / 4;
    k_cast_all<<<n4 / 256, blk, 0, stream>>>(x, Wq, Wk, Wv, W1, W2,
                                             xb, Wqkb, Wvb, W1b, W2b);
  }

  // QK projection: [8192x1024] x [2048x1024]^T -> QK [8192x2048]
  k_gemm_nt<1, 0, 0><<<dim3(2 * kD / 128, kM / 128, 1), blk, 0, stream>>>(
      xb, Wqkb, QKb, nullptr, kM, 2 * kD, kD, kD, kD, 2 * kD, 0, 0, 0);

  // Vt[b] = Wv x_b^T : [1024x1024] x [2048x1024]^T -> [1024x2048] per batch
  k_gemm_nt<1, 0, 0><<<dim3(kS / 128, kD / 128, kB), blk, 0, stream>>>(
      Wvb, xb, Vt, nullptr, kD, kS, kD, kD, kD, kS,
      0, (long)kS * kD, (long)kD * kS);

  // scores = Q K^T (bf16 out), lower-triangle compact grid
  k_gemm_nt<1, 0, 1><<<dim3(136, 1, kB), blk, 0, stream>>>(
      QKb, QKb + kD, Sb, nullptr, kS, kS, kD, 2 * kD, 2 * kD, kS,
      (long)kS * 2 * kD, (long)kS * 2 * kD, (long)kS * kS);

  // causal softmax -> P bf16 (writes only k < diagonal tile edge)
  k_softmax_causal<<<kM, blk, 0, stream>>>(Sb, Pb);

  // attn = P Vt^T (K-loop clamped at diagonal, longest-first)
  k_gemm_nt<0, 0, 2><<<dim3(kD / 128, kS / 128, kB), blk, 0, stream>>>(
      Pb, Vt, attn, nullptr, kS, kD, kS, kS, kS, kD,
      (long)kS * kS, (long)kD * kS, (long)kS * kD);

  // h = LN(x + attn), also bf16 copy
  k_residual_ln<1><<<kM, blk, 0, stream>>>(x, attn, gamma, beta, h, hb);

  // FFN
  k_gemm_nt<1, 1, 0><<<dim3(kD / 128, kM / 128, 1), blk, 0, stream>>>(
      hb, W1b, mid, b1, kM, kD, kD, kD, kD, kD, 0, 0, 0);
  k_gemm_nt<0, 0, 0><<<dim3(kD / 128, kM / 128, 1), blk, 0, stream>>>(
      mid, W2b, ff, b2, kM, kD, kD, kD, kD, kD, 0, 0, 0);

  // out = LN(h + ff)
  k_residual_ln<0><<<kM, blk, 0, stream>>>(h, ff, gamma, beta, out, nullptr);
}